// Round 15
// baseline (196.151 us; speedup 1.0000x reference)
//
#include <hip/hip_runtime.h>
#include <hip/hip_bf16.h>
#include <stdint.h>

#define BDIM 2
#define TDIM 2048
#define DDIM 2048
#define NHEADS 16
#define KVH 8
#define HDIM 128
#define WINSZ 1024
#define BT (BDIM*TDIM)      // 4096
#define NHD (NHEADS*HDIM)   // 2048
#define QKVC 4096

typedef unsigned short u16;
typedef __attribute__((ext_vector_type(8))) short bf16x8;
typedef __attribute__((ext_vector_type(4))) float f32x4;

__device__ __forceinline__ u16 f2bf(float f) {
  union { float f; unsigned u; } v; v.f = f;
  unsigned r = v.u + 0x7FFFu + ((v.u >> 16) & 1u);
  return (u16)(r >> 16);
}
__device__ __forceinline__ float bf2f(u16 u) {
  union { unsigned u; float f; } v; v.u = ((unsigned)u) << 16;
  return v.f;
}
__device__ __forceinline__ u16 cvt_bf(float f) {
  __hip_bfloat16 hb = __float2bfloat16(f);
  return *reinterpret_cast<u16*>(&hb);
}

__device__ __forceinline__ void gl_lds16(const u16* g, u16* l) {
  __builtin_amdgcn_global_load_lds((const __attribute__((address_space(1))) void*)g,
                                   (__attribute__((address_space(3))) void*)l, 16, 0, 0);
}

// ---------------- fused prep: wt_qkv | x->bf16 | wo_t | rope table ----------------
__global__ __launch_bounds__(256) void k_prep(const float* __restrict__ x, const float* __restrict__ wq,
                                              const float* __restrict__ wkv, const float* __restrict__ wo,
                                              const int* __restrict__ seg,
                                              u16* __restrict__ x_bf, u16* __restrict__ wt_qkv,
                                              u16* __restrict__ wo_t, float2* __restrict__ tab) {
  const int id = blockIdx.x, tid = threadIdx.x;
  if (id < 8192) {
    __shared__ float tl0[32][33];
    int tx = tid & 31, ty = tid >> 5;
    int r0 = (id & 127) * 32, c0 = (id >> 7) * 32;
    #pragma unroll
    for (int i = 0; i < 4; i++) {
      int r = r0 + tx, c = c0 + ty + i*8;
      const float* sp; size_t off;
      if (r < 2048) { sp = wq; off = (size_t)(r >> 7)*262144u + (size_t)(r & 127); }
      else { int j = r - 2048; sp = wkv; off = (size_t)((j >> 10)*8 + ((j >> 7) & 7))*262144u + (size_t)(j & 127); }
      off += (size_t)c * 128u;
      tl0[tx][ty + i*8] = sp[off];
    }
    __syncthreads();
    #pragma unroll
    for (int i = 0; i < 4; i++) {
      int rl = ty + i*8;
      wt_qkv[(size_t)(r0 + rl)*2048u + (size_t)(c0 + tx)] = f2bf(tl0[rl][tx]);
    }
  } else if (id < 16384) {
    int i = (id - 8192)*256 + tid;
    float4 v = ((const float4*)x)[i];
    ushort4 o;
    o.x = f2bf(v.x); o.y = f2bf(v.y); o.z = f2bf(v.z); o.w = f2bf(v.w);
    ((ushort4*)x_bf)[i] = o;
  } else if (id < 20480) {
    __shared__ float tl1[32][33];
    int id3 = id - 16384;
    int tx = tid & 31, ty = tid >> 5;
    int r0 = (id3 & 63) * 32, c0 = (id3 >> 6) * 32;
    #pragma unroll
    for (int i = 0; i < 4; i++) {
      int r = r0 + tx, c = c0 + ty + i*8;
      tl1[tx][ty + i*8] = wo[(size_t)c * 2048u + (size_t)r];
    }
    __syncthreads();
    #pragma unroll
    for (int i = 0; i < 4; i++) {
      int rl = ty + i*8;
      wo_t[(size_t)(r0 + rl)*2048u + (size_t)(c0 + tx)] = f2bf(tl1[rl][tx]);
    }
  } else {
    int bt = (id - 20480)*4 + (tid >> 6);
    int i = tid & 63;
    int pos = seg[bt];
    float inv_ts = exp2f(-(float)i * (13.287712379549449f/64.0f));
    float ang = (float)pos * inv_ts;
    tab[(size_t)bt*64 + i] = make_float2(cosf(ang), sinf(ang));
  }
}

// ---------------- 128x128 GEMM (output proj) with bijective XCD swizzle ----------------
template<int F32OUT>
__global__ __launch_bounds__(256) void k_gemm(const u16* __restrict__ A, const u16* __restrict__ Bt,
                                              void* __restrict__ Cout, int M, int Ncols, int Kdim, int ldc) {
  __shared__ u16 As[128*64];
  __shared__ u16 Bs[128*64];
  const int tid = threadIdx.x, lane = tid & 63, wave = tid >> 6;
  const int bid = blockIdx.x;
  const int xcd = bid & 7, idx = bid >> 3;
  const int m0 = (((xcd & 3) << 3) + (idx & 7)) * 128;
  const int n0 = (((xcd >> 2) << 3) + (idx >> 3)) * 128;
  const int wr = wave >> 1, wc = wave & 1;
  const int l15 = lane & 15, lg = lane >> 4;
  f32x4 acc[4][4] = {};
  for (int kt = 0; kt < Kdim; kt += 64) {
    __syncthreads();
    #pragma unroll
    for (int i = 0; i < 4; i++) {
      int chb = i*256 + wave*64;
      int ch = chb + lane;
      int r = ch >> 3, cc = ch & 7;
      gl_lds16(A + (size_t)(m0 + r)*Kdim + kt + cc*8, As + chb*8);
      gl_lds16(Bt + (size_t)(n0 + r)*Kdim + kt + cc*8, Bs + chb*8);
    }
    __syncthreads();
    #pragma unroll
    for (int ks = 0; ks < 2; ks++) {
      bf16x8 af[4], bf[4];
      int kk = ks*32 + lg*8;
      #pragma unroll
      for (int mt = 0; mt < 4; mt++) af[mt] = *(const bf16x8*)(As + (wr*64 + mt*16 + l15)*64 + kk);
      #pragma unroll
      for (int nt = 0; nt < 4; nt++) bf[nt] = *(const bf16x8*)(Bs + (wc*64 + nt*16 + l15)*64 + kk);
      #pragma unroll
      for (int mt = 0; mt < 4; mt++)
        #pragma unroll
        for (int nt = 0; nt < 4; nt++)
          acc[mt][nt] = __builtin_amdgcn_mfma_f32_16x16x32_bf16(af[mt], bf[nt], acc[mt][nt], 0, 0, 0);
    }
  }
  #pragma unroll
  for (int mt = 0; mt < 4; mt++) {
    int row = m0 + wr*64 + mt*16 + lg*4;
    #pragma unroll
    for (int nt = 0; nt < 4; nt++) {
      int col = n0 + wc*64 + nt*16 + l15;
      #pragma unroll
      for (int j = 0; j < 4; j++) {
        if (F32OUT) ((float*)Cout)[(size_t)(row + j)*ldc + col] = acc[mt][nt][j];
        else        ((u16*)Cout)[(size_t)(row + j)*ldc + col] = f2bf(acc[mt][nt][j]);
      }
    }
  }
}

// ---------------- 256x256 8-phase QKV GEMM: fused RoPE epilogue + direct V-transpose ----------------
__global__ __launch_bounds__(512, 2) void k_gemm8(const u16* __restrict__ A, const u16* __restrict__ Bt,
                                                  u16* __restrict__ Cout, u16* __restrict__ vT,
                                                  const float2* __restrict__ tab,
                                                  int M, int Ncols, int Kdim, int ldc) {
  __shared__ u16 As[2][256*64];
  __shared__ u16 Bs[2][256*64];
  const int tid = threadIdx.x, lane = tid & 63, wave = tid >> 6;
  const int l15 = lane & 15, lg = lane >> 4;
  const int wm = wave >> 2, wn = wave & 3;
  const int gx = M >> 8, gy = Ncols >> 8;
  const int nwg = gx * gy;
  int bid = blockIdx.x;
  int q = nwg >> 3, r = nwg & 7;
  int xcd = bid & 7, idx = bid >> 3;
  int wg = (xcd < r ? xcd*(q+1) : r*(q+1) + (xcd - r)*q) + idx;
  const int m0 = (wg % gx) * 256, n0 = (wg / gx) * 256;

  const int st_r = tid >> 3;
  const int st_c = (tid & 7) ^ (st_r & 7);

  const u16* Ag = A + (size_t)(m0 + st_r)*Kdim + st_c*8;
  const u16* Bg = Bt + (size_t)(n0 + st_r)*Kdim + st_c*8;

  auto stage = [&](int t, int h) {
    int buf = t & 1;
    if (h < 2) {
      const u16* g = Bg + (size_t)(h*128)*Kdim + t*64;
      u16* d = &Bs[buf][h*8192 + wave*512];
      gl_lds16(g, d);
      gl_lds16(g + (size_t)64*Kdim, d + 4096);
    } else {
      int hh = h - 2;
      const u16* g = Ag + (size_t)(hh*128)*Kdim + t*64;
      u16* d = &As[buf][hh*8192 + wave*512];
      gl_lds16(g, d);
      gl_lds16(g + (size_t)64*Kdim, d + 4096);
    }
  };

  const int aBase = (wm*128 + l15) * 128;
  const int bBase = (wn*16 + l15) * 128;     // stride-64 B-slices
  const int kx0 = ((lg) ^ (l15 & 7)) << 4;
  const int kx1 = ((4 + lg) ^ (l15 & 7)) << 4;

  f32x4 acc[8][4] = {};
  bf16x8 af[4][2], bfr[4][2];

  stage(0,0); stage(0,1); stage(0,2); stage(0,3);
  asm volatile("s_waitcnt vmcnt(4)" ::: "memory");
  stage(1,0); stage(1,1); stage(1,2);
  asm volatile("s_waitcnt vmcnt(6)" ::: "memory");
  __builtin_amdgcn_s_barrier();

  const int NT = Kdim >> 6;

#define MFMA_Q(MS, NS)                                                          \
  { _Pragma("unroll") for (int mf = 0; mf < 4; mf++)                            \
    _Pragma("unroll") for (int nf = 0; nf < 2; nf++) {                          \
      acc[(MS)+mf][(NS)+nf] = __builtin_amdgcn_mfma_f32_16x16x32_bf16(af[mf][0], bfr[(NS)+nf][0], acc[(MS)+mf][(NS)+nf], 0, 0, 0); \
      acc[(MS)+mf][(NS)+nf] = __builtin_amdgcn_mfma_f32_16x16x32_bf16(af[mf][1], bfr[(NS)+nf][1], acc[(MS)+mf][(NS)+nf], 0, 0, 0); \
  } }

  for (int t = 0; t < NT; ++t) {
    const int cur = t & 1;
    const char* Ab = (const char*)&As[cur][0];
    const char* Bb = (const char*)&Bs[cur][0];
    #pragma unroll
    for (int mf = 0; mf < 4; mf++) {
      af[mf][0] = *(const bf16x8*)(Ab + aBase + mf*2048 + kx0);
      af[mf][1] = *(const bf16x8*)(Ab + aBase + mf*2048 + kx1);
    }
    #pragma unroll
    for (int nf = 0; nf < 2; nf++) {
      bfr[nf][0] = *(const bf16x8*)(Bb + bBase + nf*8192 + kx0);
      bfr[nf][1] = *(const bf16x8*)(Bb + bBase + nf*8192 + kx1);
    }
    if (t + 1 < NT) stage(t+1, 3);
    asm volatile("s_waitcnt lgkmcnt(8)" ::: "memory");
    __builtin_amdgcn_s_barrier();
    asm volatile("" ::: "memory");
    __builtin_amdgcn_s_setprio(1);
    MFMA_Q(0, 0)
    __builtin_amdgcn_s_setprio(0);
    __builtin_amdgcn_s_barrier();
    #pragma unroll
    for (int nf = 2; nf < 4; nf++) {
      bfr[nf][0] = *(const bf16x8*)(Bb + bBase + nf*8192 + kx0);
      bfr[nf][1] = *(const bf16x8*)(Bb + bBase + nf*8192 + kx1);
    }
    __builtin_amdgcn_s_barrier();
    asm volatile("" ::: "memory");
    __builtin_amdgcn_s_setprio(1);
    MFMA_Q(0, 2)
    __builtin_amdgcn_s_setprio(0);
    __builtin_amdgcn_s_barrier();
    #pragma unroll
    for (int mf = 0; mf < 4; mf++) {
      af[mf][0] = *(const bf16x8*)(Ab + aBase + 8192 + mf*2048 + kx0);
      af[mf][1] = *(const bf16x8*)(Ab + aBase + 8192 + mf*2048 + kx1);
    }
    if (t + 2 < NT) { stage(t+2, 0); stage(t+2, 1); }
    __builtin_amdgcn_s_barrier();
    asm volatile("" ::: "memory");
    __builtin_amdgcn_s_setprio(1);
    MFMA_Q(4, 2)
    __builtin_amdgcn_s_setprio(0);
    __builtin_amdgcn_s_barrier();
    if (t + 2 < NT) {
      stage(t+2, 2);
      asm volatile("s_waitcnt vmcnt(6)" ::: "memory");
    } else if (t + 1 < NT) {
      asm volatile("s_waitcnt vmcnt(0)" ::: "memory");
    }
    __builtin_amdgcn_s_barrier();
    asm volatile("" ::: "memory");
    __builtin_amdgcn_s_setprio(1);
    MFMA_Q(4, 0)
    __builtin_amdgcn_s_setprio(0);
    __builtin_amdgcn_s_barrier();
  }
#undef MFMA_Q

  const int type = (n0 < 2048) ? 0 : (n0 < 3072 ? 1 : 2);
  const float SC = 0.08838834764831845f;
  #pragma unroll
  for (int mf = 0; mf < 8; mf++) {
    int row = m0 + wm*128 + mf*16 + lg*4;
    if (type < 2) {
      #pragma unroll
      for (int j = 0; j < 4; j++) {
        float2 cs = tab[(size_t)(row + j)*64 + wn*16 + l15];
        #pragma unroll
        for (int pp = 0; pp < 4; pp += 2) {
          float f = acc[mf][pp][j], s = acc[mf][pp+1][j];
          float oa = f*cs.x - s*cs.y;
          float ob = s*cs.x + f*cs.y;
          if (type == 0) { oa *= SC; ob *= SC; }
          int col = n0 + pp*64 + wn*16 + l15;
          Cout[(size_t)(row + j)*ldc + col]      = cvt_bf(oa);
          Cout[(size_t)(row + j)*ldc + col + 64] = cvt_bf(ob);
        }
      }
    } else {
      int bb = row >> 11, tt = row & 2047;
      #pragma unroll
      for (int nf = 0; nf < 4; nf++) {
        int cb = n0 + nf*64 + wn*16 + l15 - 3072;
        int kvhh = cb >> 7, hh = cb & 127;
        ushort4 vv;
        vv.x = f2bf(acc[mf][nf][0]); vv.y = f2bf(acc[mf][nf][1]);
        vv.z = f2bf(acc[mf][nf][2]); vv.w = f2bf(acc[mf][nf][3]);
        *(ushort4*)(vT + ((size_t)(bb*KVH + kvhh)*HDIM + hh)*TDIM + tt) = vv;
      }
    }
  }
}

// ---------------- flash attention: 72KB LDS (Pl halved) -> true 2 blocks/CU ----------------
__device__ __forceinline__ void stage_tiles(const u16* __restrict__ kg, const u16* __restrict__ vg,
                                            u16* ldsK, u16* ldsV, int tid) {
  const int w = tid >> 6;
  const int rK = tid >> 4, cK = tid & 15;
  u16* dK = ldsK + w*512;
  gl_lds16(kg + (size_t)rK*QKVC + ((cK ^ (rK & 15)) << 3), dK);
  gl_lds16(kg + (size_t)(rK + 32)*QKVC + ((cK ^ ((rK + 32) & 15)) << 3), dK + 4096);
  const int rV = tid >> 3, cV = tid & 7;
  u16* dV = ldsV + w*512;
  gl_lds16(vg + (size_t)rV*TDIM + ((cV ^ (rV & 7)) << 3), dV);
  gl_lds16(vg + (size_t)(rV + 64)*TDIM + ((cV ^ ((rV + 64) & 7)) << 3), dV + 4096);
}

__global__ __launch_bounds__(512, 4) void k_attn(const u16* __restrict__ qkv, const u16* __restrict__ vT,
                                                 u16* __restrict__ enc) {
  __shared__ u16 Kb[2][64*128];   // 32 KB
  __shared__ u16 Vb[2][128*64];   // 32 KB
  __shared__ u16 Pl[8][16*32];    //  8 KB  (PV in two 32-col halves)
  const int tid = threadIdx.x;
  const int lane = tid & 63, wave = tid >> 6;
  const int l15 = lane & 15, lg = lane >> 4;
  const int wg = blockIdx.x;
  const int lin = (wg & 7)*64 + (wg >> 3);
  const int qt = lin & 31, kvh = (lin >> 5) & 7, b = lin >> 8;
  const int n = kvh*2 + (wave >> 2);
  const int t0 = qt * 64;
  const int lo_row = t0 + (wave & 3)*16, hi_row = lo_row + 15;

  bf16x8 qf[4];
  {
    const u16* qb = qkv + (size_t)(b*TDIM + lo_row + l15)*QKVC + n*HDIM + lg*8;
    #pragma unroll
    for (int ks = 0; ks < 4; ks++) qf[ks] = *(const bf16x8*)(qb + ks*32);
  }
  f32x4 o[8] = {};
  f32x4 o_l = {};
  const short one_bf = (short)0x3F80;
  const bf16x8 ones = {one_bf, one_bf, one_bf, one_bf, one_bf, one_bf, one_bf, one_bf};

  const u16* kgb = qkv + (size_t)(b*TDIM)*QKVC + 2048 + kvh*HDIM;
  const u16* vgb = vT + (size_t)(b*KVH + kvh)*HDIM*TDIM;

  const float L0 = 1.4426950408889634f;
  const float L1 = -1.9235933878519513e-4f;
  const float L2 = 3.0777094205631089e-8f;
  const float BIAS = -72.13475204444817f;

  const int s_begin = (t0 >= 1024) ? (t0 - 1024) : 0;
  stage_tiles(kgb + (size_t)s_begin*QKVC, vgb + s_begin, Kb[0], Vb[0], tid);
  int cur = 0;
  for (int s0 = s_begin; s0 <= t0; s0 += 64) {
    if (s0 + 64 <= t0) {
      stage_tiles(kgb + (size_t)(s0 + 64)*QKVC, vgb + (s0 + 64), Kb[cur ^ 1], Vb[cur ^ 1], tid);
      asm volatile("s_waitcnt vmcnt(4)" ::: "memory");
    } else {
      asm volatile("s_waitcnt vmcnt(0)" ::: "memory");
    }
    __builtin_amdgcn_s_barrier();
    __builtin_amdgcn_sched_barrier(0);

    const u16* Kc = Kb[cur];
    const u16* Vc = Vb[cur];
    f32x4 sc4[4];
    #pragma unroll
    for (int c = 0; c < 4; c++) {
      const int cLo = s0 + c*16;
      bool anyLive = (cLo <= hi_row) && (cLo + 15 >= lo_row - (WINSZ - 1));
      bool full    = (cLo + 15 <= lo_row) && (cLo >= hi_row - (WINSZ - 1));
      f32x4 a = {0.f, 0.f, 0.f, 0.f};
      if (anyLive) {
        int krow = c*16 + l15;
        __builtin_amdgcn_s_setprio(1);
        #pragma unroll
        for (int ks = 0; ks < 4; ks++) {
          bf16x8 kf = *(const bf16x8*)(Kc + krow*128 + (((ks*4 + lg) ^ l15) << 3));
          a = __builtin_amdgcn_mfma_f32_16x16x32_bf16(qf[ks], kf, a, 0, 0, 0);
        }
        __builtin_amdgcn_s_setprio(0);
        if (full) {
          #pragma unroll
          for (int j = 0; j < 4; j++) {
            float z = a[j];
            float u = z*z;
            float tt = __builtin_fmaf(u, __builtin_fmaf(u, L2, L1), L0);
            a[j] = exp2f(__builtin_fmaf(z, tt, BIAS));
          }
        } else {
          #pragma unroll
          for (int j = 0; j < 4; j++) {
            int scol = cLo + l15;
            int trow2 = lo_row + lg*4 + j;
            float z = a[j];
            float u = z*z;
            float tt = __builtin_fmaf(u, __builtin_fmaf(u, L2, L1), L0);
            float p = exp2f(__builtin_fmaf(z, tt, BIAS));
            bool ok = (scol <= trow2) && (scol >= trow2 - (WINSZ - 1));
            a[j] = ok ? p : 0.f;
          }
        }
      }
      sc4[c] = a;
    }
    // PV in two 32-col halves; Pl layout/swizzle verified in R13's passing run.
    __builtin_amdgcn_s_setprio(1);
    #pragma unroll
    for (int h = 0; h < 2; h++) {
      #pragma unroll
      for (int c2 = 0; c2 < 2; c2++) {
        int c = h*2 + c2;
        #pragma unroll
        for (int j = 0; j < 4; j++) {
          int prow = lg*4 + j, pcol = c2*16 + l15;
          int off = prow*64 + pcol*2; off ^= (prow & 3) << 4;
          *(u16*)((char*)(&Pl[wave][0]) + off) = cvt_bf(sc4[c][j]);
        }
      }
      int roff = l15*64 + ((lg ^ (l15 & 3)) << 4);
      bf16x8 pf = *(const bf16x8*)((char*)(&Pl[wave][0]) + roff);
      o_l = __builtin_amdgcn_mfma_f32_16x16x32_bf16(pf, ones, o_l, 0, 0, 0);
      #pragma unroll
      for (int ct = 0; ct < 8; ct++) {
        int vrow = ct*16 + l15;
        bf16x8 vf = *(const bf16x8*)(Vc + vrow*64 + (((h*4 + lg) ^ (l15 & 7)) << 3));
        o[ct] = __builtin_amdgcn_mfma_f32_16x16x32_bf16(pf, vf, o[ct], 0, 0, 0);
      }
      asm volatile("" ::: "memory");   // keep h=1 P-writes after h=0 pf read
    }
    __builtin_amdgcn_s_setprio(0);
    __builtin_amdgcn_s_barrier();
    cur ^= 1;
  }
  #pragma unroll
  for (int j = 0; j < 4; j++) {
    float inv = __fdividef(1.f, o_l[j]);
    int row = lo_row + lg*4 + j;
    u16* eb = enc + (size_t)(b*TDIM + row)*NHD + n*HDIM;
    #pragma unroll
    for (int ct = 0; ct < 8; ct++)
      eb[ct*16 + l15] = cvt_bf(o[ct][j] * inv);
  }
}

extern "C" void kernel_launch(void* const* d_in, const int* in_sizes, int n_in,
                              void* d_out, int out_size, void* d_ws, size_t ws_size,
                              hipStream_t stream) {
  const float* x   = (const float*)d_in[0];
  const float* wq  = (const float*)d_in[1];
  const float* wkv = (const float*)d_in[2];
  const float* wo  = (const float*)d_in[3];
  const int*   seg = (const int*)d_in[4];
  float* out = (float*)d_out;

  char* ws = (char*)d_ws;
  u16*    x_bf   = (u16*)(ws);                       // 16 MB
  u16*    wt_qkv = (u16*)(ws + (16u << 20));         // 16 MB
  u16*    qkv    = (u16*)(ws + (32u << 20));         // 32 MB
  u16*    vT     = (u16*)(ws + (64u << 20));         //  8 MB
  u16*    enc    = (u16*)(ws + (72u << 20));         // 16 MB
  u16*    wo_t   = (u16*)(ws + (88u << 20));         //  8 MB
  float2* tab    = (float2*)(ws + (96u << 20));      //  2 MB

  k_prep<<<dim3(21504), 256, 0, stream>>>(x, wq, wkv, wo, seg, x_bf, wt_qkv, wo_t, tab);
  k_gemm8<<<dim3((BT/256)*(QKVC/256)), 512, 0, stream>>>(x_bf, wt_qkv, qkv, vT, tab, BT, QKVC, DDIM, QKVC);
  k_attn<<<dim3(512), 512, 0, stream>>>(qkv, vT, enc);
  k_gemm<1><<<dim3(512), 256, 0, stream>>>(enc, wo_t, out, BT, DDIM, NHD, DDIM);
}

// Round 16
// 196.008 us; speedup vs baseline: 1.0007x; 1.0007x over previous
//
#include <hip/hip_runtime.h>
#include <hip/hip_bf16.h>
#include <stdint.h>

#define BDIM 2
#define TDIM 2048
#define DDIM 2048
#define NHEADS 16
#define KVH 8
#define HDIM 128
#define WINSZ 1024
#define BT (BDIM*TDIM)      // 4096
#define NHD (NHEADS*HDIM)   // 2048
#define QKVC 4096

typedef unsigned short u16;
typedef __attribute__((ext_vector_type(8))) short bf16x8;
typedef __attribute__((ext_vector_type(4))) float f32x4;

__device__ __forceinline__ u16 f2bf(float f) {
  union { float f; unsigned u; } v; v.f = f;
  unsigned r = v.u + 0x7FFFu + ((v.u >> 16) & 1u);
  return (u16)(r >> 16);
}
__device__ __forceinline__ float bf2f(u16 u) {
  union { unsigned u; float f; } v; v.u = ((unsigned)u) << 16;
  return v.f;
}
__device__ __forceinline__ u16 cvt_bf(float f) {
  __hip_bfloat16 hb = __float2bfloat16(f);
  return *reinterpret_cast<u16*>(&hb);
}

__device__ __forceinline__ void gl_lds16(const u16* g, u16* l) {
  __builtin_amdgcn_global_load_lds((const __attribute__((address_space(1))) void*)g,
                                   (__attribute__((address_space(3))) void*)l, 16, 0, 0);
}

// ---------------- fused prep: wt_qkv | x->bf16 | wo_t | rope table ----------------
__global__ __launch_bounds__(256) void k_prep(const float* __restrict__ x, const float* __restrict__ wq,
                                              const float* __restrict__ wkv, const float* __restrict__ wo,
                                              const int* __restrict__ seg,
                                              u16* __restrict__ x_bf, u16* __restrict__ wt_qkv,
                                              u16* __restrict__ wo_t, float2* __restrict__ tab) {
  const int id = blockIdx.x, tid = threadIdx.x;
  if (id < 8192) {
    __shared__ float tl0[32][33];
    int tx = tid & 31, ty = tid >> 5;
    int r0 = (id & 127) * 32, c0 = (id >> 7) * 32;
    #pragma unroll
    for (int i = 0; i < 4; i++) {
      int r = r0 + tx, c = c0 + ty + i*8;
      const float* sp; size_t off;
      if (r < 2048) { sp = wq; off = (size_t)(r >> 7)*262144u + (size_t)(r & 127); }
      else { int j = r - 2048; sp = wkv; off = (size_t)((j >> 10)*8 + ((j >> 7) & 7))*262144u + (size_t)(j & 127); }
      off += (size_t)c * 128u;
      tl0[tx][ty + i*8] = sp[off];
    }
    __syncthreads();
    #pragma unroll
    for (int i = 0; i < 4; i++) {
      int rl = ty + i*8;
      wt_qkv[(size_t)(r0 + rl)*2048u + (size_t)(c0 + tx)] = f2bf(tl0[rl][tx]);
    }
  } else if (id < 16384) {
    int i = (id - 8192)*256 + tid;
    float4 v = ((const float4*)x)[i];
    ushort4 o;
    o.x = f2bf(v.x); o.y = f2bf(v.y); o.z = f2bf(v.z); o.w = f2bf(v.w);
    ((ushort4*)x_bf)[i] = o;
  } else if (id < 20480) {
    __shared__ float tl1[32][33];
    int id3 = id - 16384;
    int tx = tid & 31, ty = tid >> 5;
    int r0 = (id3 & 63) * 32, c0 = (id3 >> 6) * 32;
    #pragma unroll
    for (int i = 0; i < 4; i++) {
      int r = r0 + tx, c = c0 + ty + i*8;
      tl1[tx][ty + i*8] = wo[(size_t)c * 2048u + (size_t)r];
    }
    __syncthreads();
    #pragma unroll
    for (int i = 0; i < 4; i++) {
      int rl = ty + i*8;
      wo_t[(size_t)(r0 + rl)*2048u + (size_t)(c0 + tx)] = f2bf(tl1[rl][tx]);
    }
  } else {
    int bt = (id - 20480)*4 + (tid >> 6);
    int i = tid & 63;
    int pos = seg[bt];
    float inv_ts = exp2f(-(float)i * (13.287712379549449f/64.0f));
    float ang = (float)pos * inv_ts;
    tab[(size_t)bt*64 + i] = make_float2(cosf(ang), sinf(ang));
  }
}

// ---------------- 128x128 GEMM (output proj) with bijective XCD swizzle ----------------
template<int F32OUT>
__global__ __launch_bounds__(256) void k_gemm(const u16* __restrict__ A, const u16* __restrict__ Bt,
                                              void* __restrict__ Cout, int M, int Ncols, int Kdim, int ldc) {
  __shared__ u16 As[128*64];
  __shared__ u16 Bs[128*64];
  const int tid = threadIdx.x, lane = tid & 63, wave = tid >> 6;
  const int bid = blockIdx.x;
  const int xcd = bid & 7, idx = bid >> 3;
  const int m0 = (((xcd & 3) << 3) + (idx & 7)) * 128;
  const int n0 = (((xcd >> 2) << 3) + (idx >> 3)) * 128;
  const int wr = wave >> 1, wc = wave & 1;
  const int l15 = lane & 15, lg = lane >> 4;
  f32x4 acc[4][4] = {};
  for (int kt = 0; kt < Kdim; kt += 64) {
    __syncthreads();
    #pragma unroll
    for (int i = 0; i < 4; i++) {
      int chb = i*256 + wave*64;
      int ch = chb + lane;
      int r = ch >> 3, cc = ch & 7;
      gl_lds16(A + (size_t)(m0 + r)*Kdim + kt + cc*8, As + chb*8);
      gl_lds16(Bt + (size_t)(n0 + r)*Kdim + kt + cc*8, Bs + chb*8);
    }
    __syncthreads();
    #pragma unroll
    for (int ks = 0; ks < 2; ks++) {
      bf16x8 af[4], bf[4];
      int kk = ks*32 + lg*8;
      #pragma unroll
      for (int mt = 0; mt < 4; mt++) af[mt] = *(const bf16x8*)(As + (wr*64 + mt*16 + l15)*64 + kk);
      #pragma unroll
      for (int nt = 0; nt < 4; nt++) bf[nt] = *(const bf16x8*)(Bs + (wc*64 + nt*16 + l15)*64 + kk);
      #pragma unroll
      for (int mt = 0; mt < 4; mt++)
        #pragma unroll
        for (int nt = 0; nt < 4; nt++)
          acc[mt][nt] = __builtin_amdgcn_mfma_f32_16x16x32_bf16(af[mt], bf[nt], acc[mt][nt], 0, 0, 0);
    }
  }
  #pragma unroll
  for (int mt = 0; mt < 4; mt++) {
    int row = m0 + wr*64 + mt*16 + lg*4;
    #pragma unroll
    for (int nt = 0; nt < 4; nt++) {
      int col = n0 + wc*64 + nt*16 + l15;
      #pragma unroll
      for (int j = 0; j < 4; j++) {
        if (F32OUT) ((float*)Cout)[(size_t)(row + j)*ldc + col] = acc[mt][nt][j];
        else        ((u16*)Cout)[(size_t)(row + j)*ldc + col] = f2bf(acc[mt][nt][j]);
      }
    }
  }
}

// ---------------- 256x256 8-phase QKV GEMM: fused RoPE epilogue + direct V-transpose ----------------
__global__ __launch_bounds__(512, 2) void k_gemm8(const u16* __restrict__ A, const u16* __restrict__ Bt,
                                                  u16* __restrict__ Cout, u16* __restrict__ vT,
                                                  const float2* __restrict__ tab,
                                                  int M, int Ncols, int Kdim, int ldc) {
  __shared__ u16 As[2][256*64];
  __shared__ u16 Bs[2][256*64];
  const int tid = threadIdx.x, lane = tid & 63, wave = tid >> 6;
  const int l15 = lane & 15, lg = lane >> 4;
  const int wm = wave >> 2, wn = wave & 3;
  const int gx = M >> 8, gy = Ncols >> 8;
  const int nwg = gx * gy;
  int bid = blockIdx.x;
  int q = nwg >> 3, r = nwg & 7;
  int xcd = bid & 7, idx = bid >> 3;
  int wg = (xcd < r ? xcd*(q+1) : r*(q+1) + (xcd - r)*q) + idx;
  const int m0 = (wg % gx) * 256, n0 = (wg / gx) * 256;

  const int st_r = tid >> 3;
  const int st_c = (tid & 7) ^ (st_r & 7);

  const u16* Ag = A + (size_t)(m0 + st_r)*Kdim + st_c*8;
  const u16* Bg = Bt + (size_t)(n0 + st_r)*Kdim + st_c*8;

  auto stage = [&](int t, int h) {
    int buf = t & 1;
    if (h < 2) {
      const u16* g = Bg + (size_t)(h*128)*Kdim + t*64;
      u16* d = &Bs[buf][h*8192 + wave*512];
      gl_lds16(g, d);
      gl_lds16(g + (size_t)64*Kdim, d + 4096);
    } else {
      int hh = h - 2;
      const u16* g = Ag + (size_t)(hh*128)*Kdim + t*64;
      u16* d = &As[buf][hh*8192 + wave*512];
      gl_lds16(g, d);
      gl_lds16(g + (size_t)64*Kdim, d + 4096);
    }
  };

  const int aBase = (wm*128 + l15) * 128;
  const int bBase = (wn*16 + l15) * 128;     // stride-64 B-slices
  const int kx0 = ((lg) ^ (l15 & 7)) << 4;
  const int kx1 = ((4 + lg) ^ (l15 & 7)) << 4;

  f32x4 acc[8][4] = {};
  bf16x8 af[4][2], bfr[4][2];

  stage(0,0); stage(0,1); stage(0,2); stage(0,3);
  asm volatile("s_waitcnt vmcnt(4)" ::: "memory");
  stage(1,0); stage(1,1); stage(1,2);
  asm volatile("s_waitcnt vmcnt(6)" ::: "memory");
  __builtin_amdgcn_s_barrier();

  const int NT = Kdim >> 6;

#define MFMA_Q(MS, NS)                                                          \
  { _Pragma("unroll") for (int mf = 0; mf < 4; mf++)                            \
    _Pragma("unroll") for (int nf = 0; nf < 2; nf++) {                          \
      acc[(MS)+mf][(NS)+nf] = __builtin_amdgcn_mfma_f32_16x16x32_bf16(af[mf][0], bfr[(NS)+nf][0], acc[(MS)+mf][(NS)+nf], 0, 0, 0); \
      acc[(MS)+mf][(NS)+nf] = __builtin_amdgcn_mfma_f32_16x16x32_bf16(af[mf][1], bfr[(NS)+nf][1], acc[(MS)+mf][(NS)+nf], 0, 0, 0); \
  } }

  for (int t = 0; t < NT; ++t) {
    const int cur = t & 1;
    const char* Ab = (const char*)&As[cur][0];
    const char* Bb = (const char*)&Bs[cur][0];
    #pragma unroll
    for (int mf = 0; mf < 4; mf++) {
      af[mf][0] = *(const bf16x8*)(Ab + aBase + mf*2048 + kx0);
      af[mf][1] = *(const bf16x8*)(Ab + aBase + mf*2048 + kx1);
    }
    #pragma unroll
    for (int nf = 0; nf < 2; nf++) {
      bfr[nf][0] = *(const bf16x8*)(Bb + bBase + nf*8192 + kx0);
      bfr[nf][1] = *(const bf16x8*)(Bb + bBase + nf*8192 + kx1);
    }
    if (t + 1 < NT) stage(t+1, 3);
    asm volatile("s_waitcnt lgkmcnt(8)" ::: "memory");
    __builtin_amdgcn_s_barrier();
    asm volatile("" ::: "memory");
    __builtin_amdgcn_s_setprio(1);
    MFMA_Q(0, 0)
    __builtin_amdgcn_s_setprio(0);
    __builtin_amdgcn_s_barrier();
    #pragma unroll
    for (int nf = 2; nf < 4; nf++) {
      bfr[nf][0] = *(const bf16x8*)(Bb + bBase + nf*8192 + kx0);
      bfr[nf][1] = *(const bf16x8*)(Bb + bBase + nf*8192 + kx1);
    }
    __builtin_amdgcn_s_barrier();
    asm volatile("" ::: "memory");
    __builtin_amdgcn_s_setprio(1);
    MFMA_Q(0, 2)
    __builtin_amdgcn_s_setprio(0);
    __builtin_amdgcn_s_barrier();
    #pragma unroll
    for (int mf = 0; mf < 4; mf++) {
      af[mf][0] = *(const bf16x8*)(Ab + aBase + 8192 + mf*2048 + kx0);
      af[mf][1] = *(const bf16x8*)(Ab + aBase + 8192 + mf*2048 + kx1);
    }
    if (t + 2 < NT) { stage(t+2, 0); stage(t+2, 1); }
    __builtin_amdgcn_s_barrier();
    asm volatile("" ::: "memory");
    __builtin_amdgcn_s_setprio(1);
    MFMA_Q(4, 2)
    __builtin_amdgcn_s_setprio(0);
    __builtin_amdgcn_s_barrier();
    if (t + 2 < NT) {
      stage(t+2, 2);
      asm volatile("s_waitcnt vmcnt(6)" ::: "memory");
    } else if (t + 1 < NT) {
      asm volatile("s_waitcnt vmcnt(0)" ::: "memory");
    }
    __builtin_amdgcn_s_barrier();
    asm volatile("" ::: "memory");
    __builtin_amdgcn_s_setprio(1);
    MFMA_Q(4, 0)
    __builtin_amdgcn_s_setprio(0);
    __builtin_amdgcn_s_barrier();
  }
#undef MFMA_Q

  const int type = (n0 < 2048) ? 0 : (n0 < 3072 ? 1 : 2);
  const float SC = 0.08838834764831845f;
  #pragma unroll
  for (int mf = 0; mf < 8; mf++) {
    int row = m0 + wm*128 + mf*16 + lg*4;
    if (type < 2) {
      #pragma unroll
      for (int j = 0; j < 4; j++) {
        float2 cs = tab[(size_t)(row + j)*64 + wn*16 + l15];
        #pragma unroll
        for (int pp = 0; pp < 4; pp += 2) {
          float f = acc[mf][pp][j], s = acc[mf][pp+1][j];
          float oa = f*cs.x - s*cs.y;
          float ob = s*cs.x + f*cs.y;
          if (type == 0) { oa *= SC; ob *= SC; }
          int col = n0 + pp*64 + wn*16 + l15;
          Cout[(size_t)(row + j)*ldc + col]      = cvt_bf(oa);
          Cout[(size_t)(row + j)*ldc + col + 64] = cvt_bf(ob);
        }
      }
    } else {
      int bb = row >> 11, tt = row & 2047;
      #pragma unroll
      for (int nf = 0; nf < 4; nf++) {
        int cb = n0 + nf*64 + wn*16 + l15 - 3072;
        int kvhh = cb >> 7, hh = cb & 127;
        ushort4 vv;
        vv.x = f2bf(acc[mf][nf][0]); vv.y = f2bf(acc[mf][nf][1]);
        vv.z = f2bf(acc[mf][nf][2]); vv.w = f2bf(acc[mf][nf][3]);
        *(ushort4*)(vT + ((size_t)(bb*KVH + kvhh)*HDIM + hh)*TDIM + tt) = vv;
      }
    }
  }
}

// ---------------- flash attention: LPT dispatch (heavy qt first) ----------------
__device__ __forceinline__ void stage_tiles(const u16* __restrict__ kg, const u16* __restrict__ vg,
                                            u16* ldsK, u16* ldsV, int tid) {
  const int w = tid >> 6;
  const int rK = tid >> 4, cK = tid & 15;
  u16* dK = ldsK + w*512;
  gl_lds16(kg + (size_t)rK*QKVC + ((cK ^ (rK & 15)) << 3), dK);
  gl_lds16(kg + (size_t)(rK + 32)*QKVC + ((cK ^ ((rK + 32) & 15)) << 3), dK + 4096);
  const int rV = tid >> 3, cV = tid & 7;
  u16* dV = ldsV + w*512;
  gl_lds16(vg + (size_t)rV*TDIM + ((cV ^ (rV & 7)) << 3), dV);
  gl_lds16(vg + (size_t)(rV + 64)*TDIM + ((cV ^ ((rV + 64) & 7)) << 3), dV + 4096);
}

__global__ __launch_bounds__(512, 4) void k_attn(const u16* __restrict__ qkv, const u16* __restrict__ vT,
                                                 u16* __restrict__ enc) {
  __shared__ u16 Kb[2][64*128];   // 32 KB
  __shared__ u16 Vb[2][128*64];   // 32 KB
  __shared__ u16 Pl[8][16*32];    //  8 KB
  const int tid = threadIdx.x;
  const int lane = tid & 63, wave = tid >> 6;
  const int l15 = lane & 15, lg = lane >> 4;
  const int wg = blockIdx.x;
  const int lin = (wg & 7)*64 + (wg >> 3);
  // LPT: heavy blocks (large qt = more K-tiles) dispatched first within each panel
  const int qt = 31 - (lin & 31), kvh = (lin >> 5) & 7, b = lin >> 8;
  const int n = kvh*2 + (wave >> 2);
  const int t0 = qt * 64;
  const int lo_row = t0 + (wave & 3)*16, hi_row = lo_row + 15;

  bf16x8 qf[4];
  {
    const u16* qb = qkv + (size_t)(b*TDIM + lo_row + l15)*QKVC + n*HDIM + lg*8;
    #pragma unroll
    for (int ks = 0; ks < 4; ks++) qf[ks] = *(const bf16x8*)(qb + ks*32);
  }
  f32x4 o[8] = {};
  f32x4 o_l = {};
  const short one_bf = (short)0x3F80;
  const bf16x8 ones = {one_bf, one_bf, one_bf, one_bf, one_bf, one_bf, one_bf, one_bf};

  const u16* kgb = qkv + (size_t)(b*TDIM)*QKVC + 2048 + kvh*HDIM;
  const u16* vgb = vT + (size_t)(b*KVH + kvh)*HDIM*TDIM;

  const float L0 = 1.4426950408889634f;
  const float L1 = -1.9235933878519513e-4f;
  const float L2 = 3.0777094205631089e-8f;
  const float BIAS = -72.13475204444817f;

  const int s_begin = (t0 >= 1024) ? (t0 - 1024) : 0;
  stage_tiles(kgb + (size_t)s_begin*QKVC, vgb + s_begin, Kb[0], Vb[0], tid);
  int cur = 0;
  for (int s0 = s_begin; s0 <= t0; s0 += 64) {
    if (s0 + 64 <= t0) {
      stage_tiles(kgb + (size_t)(s0 + 64)*QKVC, vgb + (s0 + 64), Kb[cur ^ 1], Vb[cur ^ 1], tid);
      asm volatile("s_waitcnt vmcnt(4)" ::: "memory");
    } else {
      asm volatile("s_waitcnt vmcnt(0)" ::: "memory");
    }
    __builtin_amdgcn_s_barrier();
    __builtin_amdgcn_sched_barrier(0);

    const u16* Kc = Kb[cur];
    const u16* Vc = Vb[cur];
    f32x4 sc4[4];
    #pragma unroll
    for (int c = 0; c < 4; c++) {
      const int cLo = s0 + c*16;
      bool anyLive = (cLo <= hi_row) && (cLo + 15 >= lo_row - (WINSZ - 1));
      bool full    = (cLo + 15 <= lo_row) && (cLo >= hi_row - (WINSZ - 1));
      f32x4 a = {0.f, 0.f, 0.f, 0.f};
      if (anyLive) {
        int krow = c*16 + l15;
        __builtin_amdgcn_s_setprio(1);
        #pragma unroll
        for (int ks = 0; ks < 4; ks++) {
          bf16x8 kf = *(const bf16x8*)(Kc + krow*128 + (((ks*4 + lg) ^ l15) << 3));
          a = __builtin_amdgcn_mfma_f32_16x16x32_bf16(qf[ks], kf, a, 0, 0, 0);
        }
        __builtin_amdgcn_s_setprio(0);
        if (full) {
          #pragma unroll
          for (int j = 0; j < 4; j++) {
            float z = a[j];
            float u = z*z;
            float tt = __builtin_fmaf(u, __builtin_fmaf(u, L2, L1), L0);
            a[j] = exp2f(__builtin_fmaf(z, tt, BIAS));
          }
        } else {
          #pragma unroll
          for (int j = 0; j < 4; j++) {
            int scol = cLo + l15;
            int trow2 = lo_row + lg*4 + j;
            float z = a[j];
            float u = z*z;
            float tt = __builtin_fmaf(u, __builtin_fmaf(u, L2, L1), L0);
            float p = exp2f(__builtin_fmaf(z, tt, BIAS));
            bool ok = (scol <= trow2) && (scol >= trow2 - (WINSZ - 1));
            a[j] = ok ? p : 0.f;
          }
        }
      }
      sc4[c] = a;
    }
    __builtin_amdgcn_s_setprio(1);
    #pragma unroll
    for (int h = 0; h < 2; h++) {
      #pragma unroll
      for (int c2 = 0; c2 < 2; c2++) {
        int c = h*2 + c2;
        #pragma unroll
        for (int j = 0; j < 4; j++) {
          int prow = lg*4 + j, pcol = c2*16 + l15;
          int off = prow*64 + pcol*2; off ^= (prow & 3) << 4;
          *(u16*)((char*)(&Pl[wave][0]) + off) = cvt_bf(sc4[c][j]);
        }
      }
      int roff = l15*64 + ((lg ^ (l15 & 3)) << 4);
      bf16x8 pf = *(const bf16x8*)((char*)(&Pl[wave][0]) + roff);
      o_l = __builtin_amdgcn_mfma_f32_16x16x32_bf16(pf, ones, o_l, 0, 0, 0);
      #pragma unroll
      for (int ct = 0; ct < 8; ct++) {
        int vrow = ct*16 + l15;
        bf16x8 vf = *(const bf16x8*)(Vc + vrow*64 + (((h*4 + lg) ^ (l15 & 7)) << 3));
        o[ct] = __builtin_amdgcn_mfma_f32_16x16x32_bf16(pf, vf, o[ct], 0, 0, 0);
      }
      asm volatile("" ::: "memory");
    }
    __builtin_amdgcn_s_setprio(0);
    __builtin_amdgcn_s_barrier();
    cur ^= 1;
  }
  #pragma unroll
  for (int j = 0; j < 4; j++) {
    float inv = __fdividef(1.f, o_l[j]);
    int row = lo_row + lg*4 + j;
    u16* eb = enc + (size_t)(b*TDIM + row)*NHD + n*HDIM;
    #pragma unroll
    for (int ct = 0; ct < 8; ct++)
      eb[ct*16 + l15] = cvt_bf(o[ct][j] * inv);
  }
}

extern "C" void kernel_launch(void* const* d_in, const int* in_sizes, int n_in,
                              void* d_out, int out_size, void* d_ws, size_t ws_size,
                              hipStream_t stream) {
  const float* x   = (const float*)d_in[0];
  const float* wq  = (const float*)d_in[1];
  const float* wkv = (const float*)d_in[2];
  const float* wo  = (const float*)d_in[3];
  const int*   seg = (const int*)d_in[4];
  float* out = (float*)d_out;

  char* ws = (char*)d_ws;
  u16*    x_bf   = (u16*)(ws);                       // 16 MB
  u16*    wt_qkv = (u16*)(ws + (16u << 20));         // 16 MB
  u16*    qkv    = (u16*)(ws + (32u << 20));         // 32 MB
  u16*    vT     = (u16*)(ws + (64u << 20));         //  8 MB
  u16*    enc    = (u16*)(ws + (72u << 20));         // 16 MB
  u16*    wo_t   = (u16*)(ws + (88u << 20));         //  8 MB
  float2* tab    = (float2*)(ws + (96u << 20));      //  2 MB

  k_prep<<<dim3(21504), 256, 0, stream>>>(x, wq, wkv, wo, seg, x_bf, wt_qkv, wo_t, tab);
  k_gemm8<<<dim3((BT/256)*(QKVC/256)), 512, 0, stream>>>(x_bf, wt_qkv, qkv, vT, tab, BT, QKVC, DDIM, QKVC);
  k_attn<<<dim3(512), 512, 0, stream>>>(qkv, vT, enc);
  k_gemm<1><<<dim3(512), 256, 0, stream>>>(enc, wo_t, out, BT, DDIM, NHD, DDIM);
}